// Round 6
// baseline (343.641 us; speedup 1.0000x reference)
//
#include <hip/hip_runtime.h>
#include <hip/hip_bf16.h>
#include <math.h>

// Problem constants (CausalSelfAttention_84928683311105)
#define B_  2
#define T_  2048
#define C_  2048
#define NH_ 16
#define NKV_ 4
#define HD_ 128
#define NREP_ (NH_/NKV_)     // 4

// fused QKV output layout: [B*T, 3072] ; q @ 0, k @ 2048, v @ 2560
#define QKVLD 3072
#define KOFF  2048
#define VOFF  2560

// q scale: (1/sqrt(d))^2 folded = 1/128, times log2(e) so scores are in
// log2 units and softmax exp is a single native v_exp_f32.
#define QSCALE 0.01127105500694502f

typedef __bf16 bf16x8 __attribute__((ext_vector_type(8)));
typedef float  f32x4  __attribute__((ext_vector_type(4)));

__device__ inline void gload_lds16(const void* g, void* l) {
    __builtin_amdgcn_global_load_lds((const __attribute__((address_space(1))) void*)g,
                                     (__attribute__((address_space(3))) void*)l, 16, 0, 0);
}

// ---------------------------------------------------------------------------
// cast fp32 -> bf16, 8 elems/thread
// ---------------------------------------------------------------------------
__global__ __launch_bounds__(256) void cast_bf16(const float* __restrict__ src,
                                                 __bf16* __restrict__ dst)
{
    size_t i = ((size_t)blockIdx.x * 256 + threadIdx.x) * 8;
    float4 a = *(const float4*)&src[i];
    float4 b = *(const float4*)&src[i + 4];
    union { __bf16 h[8]; uint4 u; } pk;
    pk.h[0] = (__bf16)a.x; pk.h[1] = (__bf16)a.y; pk.h[2] = (__bf16)a.z; pk.h[3] = (__bf16)a.w;
    pk.h[4] = (__bf16)b.x; pk.h[5] = (__bf16)b.y; pk.h[6] = (__bf16)b.z; pk.h[7] = (__bf16)b.w;
    *(uint4*)&dst[i] = pk.u;
}

// ---------------------------------------------------------------------------
// merged transpose-cast of Wq|Wk|Wv into wqkvT [3072, 2048] bf16.
// ---------------------------------------------------------------------------
__global__ __launch_bounds__(256) void wtrans_qkv(const float* __restrict__ Wq,
                                                  const float* __restrict__ Wk,
                                                  const float* __restrict__ Wv,
                                                  __bf16* __restrict__ dst)
{
    __shared__ float tl[32][33];
    int ct = blockIdx.x;
    int k0 = blockIdx.y * 32;
    const float* src;
    int ncols, c0, dr0;
    if (ct < 64)      { src = Wq; ncols = 2048; c0 = ct * 32;        dr0 = ct * 32; }
    else if (ct < 80) { src = Wk; ncols = 512;  c0 = (ct - 64) * 32; dr0 = KOFF + (ct - 64) * 32; }
    else              { src = Wv; ncols = 512;  c0 = (ct - 80) * 32; dr0 = VOFF + (ct - 80) * 32; }

    int tid = threadIdx.x;
    int r  = tid >> 3;
    int c4 = (tid & 7) * 4;
    float4 v = *(const float4*)&src[(size_t)(k0 + r) * ncols + c0 + c4];
    tl[r][c4] = v.x; tl[r][c4 + 1] = v.y; tl[r][c4 + 2] = v.z; tl[r][c4 + 3] = v.w;
    __syncthreads();
    union { __bf16 h[4]; uint2 u; } pk;
#pragma unroll
    for (int j = 0; j < 4; ++j) pk.h[j] = (__bf16)tl[c4 + j][r];
    *(uint2*)&dst[(size_t)(dr0 + r) * 2048 + k0 + c4] = pk.u;
}

// plain transpose-cast for Wp
__global__ __launch_bounds__(256) void wtrans(const float* __restrict__ src,
                                              __bf16* __restrict__ dst, int ncols)
{
    __shared__ float tl[32][33];
    int n0 = blockIdx.x * 32;
    int k0 = blockIdx.y * 32;
    int tid = threadIdx.x;
    int r  = tid >> 3;
    int c4 = (tid & 7) * 4;
    float4 v = *(const float4*)&src[(size_t)(k0 + r) * ncols + n0 + c4];
    tl[r][c4] = v.x; tl[r][c4 + 1] = v.y; tl[r][c4 + 2] = v.z; tl[r][c4 + 3] = v.w;
    __syncthreads();
    union { __bf16 h[4]; uint2 u; } pk;
#pragma unroll
    for (int j = 0; j < 4; ++j) pk.h[j] = (__bf16)tl[c4 + j][r];
    *(uint2*)&dst[(size_t)(n0 + r) * 2048 + k0 + c4] = pk.u;
}

// ---------------------------------------------------------------------------
// bf16 MFMA GEMM, single-barrier double-buffered: C = A(MxK) @ Bt^T, Bt [N,K].
// ---------------------------------------------------------------------------
template<typename TOUT>
__global__ __launch_bounds__(256) void gemm_bt(const __bf16* __restrict__ A,
                                               const __bf16* __restrict__ Bt,
                                               TOUT* __restrict__ C,
                                               int M, int N, int K, int ldc)
{
    __shared__ __bf16 As[2][128 * 32];
    __shared__ __bf16 Bs[2][128 * 32];

    const int tid  = threadIdx.x;
    const int wv   = tid >> 6;
    const int lane = tid & 63;
    const int grp  = lane >> 4;
    const int id16 = lane & 15;
    const int wr   = wv >> 1;
    const int wc   = wv & 1;

    const int row0 = blockIdx.y * 128;
    const int col0 = blockIdx.x * 128;

    const int sm = tid >> 2;
    const int sk = (tid & 3) << 3;

    const __bf16* ga0 = A  + (size_t)(row0 + sm) * K + sk;
    const __bf16* ga1 = A  + (size_t)(row0 + 64 + sm) * K + sk;
    const __bf16* gb0 = Bt + (size_t)(col0 + sm) * K + sk;
    const __bf16* gb1 = Bt + (size_t)(col0 + 64 + sm) * K + sk;

    f32x4 acc[4][4];
    const f32x4 fz = {0.f, 0.f, 0.f, 0.f};
#pragma unroll
    for (int i = 0; i < 4; ++i)
#pragma unroll
        for (int j = 0; j < 4; ++j) acc[i][j] = fz;

    const int nk = K >> 5;

    {
        __bf16* a0 = &As[0][wv << 9];
        __bf16* b0 = &Bs[0][wv << 9];
        gload_lds16(ga0, a0);
        gload_lds16(ga1, a0 + 2048);
        gload_lds16(gb0, b0);
        gload_lds16(gb1, b0 + 2048);
    }

    for (int kt = 0; kt < nk; ++kt) {
        const int bufc = kt & 1;
        asm volatile("s_waitcnt vmcnt(0)" ::: "memory");
        __syncthreads();

        if (kt + 1 < nk) {
            const int kb = (kt + 1) << 5;
            __bf16* a0 = &As[1 - bufc][wv << 9];
            __bf16* b0 = &Bs[1 - bufc][wv << 9];
            gload_lds16(ga0 + kb, a0);
            gload_lds16(ga1 + kb, a0 + 2048);
            gload_lds16(gb0 + kb, b0);
            gload_lds16(gb1 + kb, b0 + 2048);
        }

        bf16x8 af[4], bfr[4];
#pragma unroll
        for (int i = 0; i < 4; ++i)
            af[i] = *(const bf16x8*)&As[bufc][((wr << 6) + (i << 4) + id16) * 32 + (grp << 3)];
#pragma unroll
        for (int j = 0; j < 4; ++j)
            bfr[j] = *(const bf16x8*)&Bs[bufc][((wc << 6) + (j << 4) + id16) * 32 + (grp << 3)];
#pragma unroll
        for (int i = 0; i < 4; ++i)
#pragma unroll
            for (int j = 0; j < 4; ++j)
                acc[i][j] = __builtin_amdgcn_mfma_f32_16x16x32_bf16(af[i], bfr[j], acc[i][j], 0, 0, 0);
    }

#pragma unroll
    for (int i = 0; i < 4; ++i) {
        int gr = row0 + (wr << 6) + (i << 4) + (grp << 2);
#pragma unroll
        for (int j = 0; j < 4; ++j) {
            int gc = col0 + (wc << 6) + (j << 4) + id16;
#pragma unroll
            for (int r = 0; r < 4; ++r) {
                if constexpr (sizeof(TOUT) == 4)
                    C[(size_t)(gr + r) * ldc + gc] = acc[i][j][r];
                else
                    C[(size_t)(gr + r) * ldc + gc] = (TOUT)acc[i][j][r];
            }
        }
    }
}

// ---------------------------------------------------------------------------
// RoPE + RMSNorm in-place on bf16 head-vectors inside the strided qkv buffer.
// ---------------------------------------------------------------------------
__global__ __launch_bounds__(256) void rope_rms_b(__bf16* __restrict__ base,
                                                  const float* __restrict__ cosb,
                                                  const float* __restrict__ sinb,
                                                  int nheads, float scale)
{
    int wid  = blockIdx.x * 4 + (threadIdx.x >> 6);
    int lane = threadIdx.x & 63;
    int bt = wid / nheads;
    int hd = wid % nheads;
    int t  = bt % T_;

    __bf16* p = base + (size_t)bt * QKVLD + hd * HD_;
    float c = cosb[t * 64 + lane];
    float s = sinb[t * 64 + lane];
    float x1 = (float)p[lane];
    float x2 = (float)p[lane + 64];
    float r1 = x1 * c - x2 * s;
    float r2 = x1 * s + x2 * c;
    float ss = r1 * r1 + r2 * r2;
#pragma unroll
    for (int off = 32; off; off >>= 1) ss += __shfl_xor(ss, off, 64);
    float inv = rsqrtf(ss * (1.f / 128.f) + 1e-6f) * scale;
    p[lane]      = (__bf16)(r1 * inv);
    p[lane + 64] = (__bf16)(r2 * inv);
}

// ---------------------------------------------------------------------------
// Transpose V out of qkv: -> vt [B,NKV,128,T] bf16.
// ---------------------------------------------------------------------------
__global__ __launch_bounds__(256) void vtrans(const __bf16* __restrict__ qkv,
                                              __bf16* __restrict__ vt)
{
    __shared__ __bf16 tl[32][HD_ + 8];
    int bx  = blockIdx.x;
    int st  = bx & 63;
    int bkv = bx >> 6;
    int b = bkv >> 2, kv = bkv & 3;
    int s0 = st << 5;
    int tid = threadIdx.x;
    {
        int s = tid >> 3;
        int d = (tid & 7) << 4;
        const __bf16* src = qkv + (size_t)(b * T_ + s0 + s) * QKVLD + VOFF + kv * HD_ + d;
        *(bf16x8*)&tl[s][d]     = *(const bf16x8*)src;
        *(bf16x8*)&tl[s][d + 8] = *(const bf16x8*)(src + 8);
    }
    __syncthreads();
    {
        int d  = tid >> 1;
        int sh = (tid & 1) << 4;
        __bf16 tmp[16];
#pragma unroll
        for (int j = 0; j < 16; ++j) tmp[j] = tl[sh + j][d];
        __bf16* dst = vt + ((size_t)(b * NKV_ + kv) * HD_ + d) * T_ + s0 + sh;
        *(bf16x8*)dst       = *(bf16x8*)&tmp[0];
        *(bf16x8*)(dst + 8) = *(bf16x8*)&tmp[8];
    }
}

// ---------------------------------------------------------------------------
// Flash attention v4: 2 waves/block, 32 q-rows per wave (two 16-row sets qt).
// Every K/V LDS fragment read now feeds 2 MFMAs -> per-FLOP LDS traffic
// halves vs v3 (the measured bottleneck). KT=64 dbuf + XOR swizzle staging,
// fixed-max softmax (|score| <= 1 by Cauchy-Schwarz on RMS-normed q,k),
// pairing (j, 31-j): 512 equal blocks of 33 key-tiles, 2 blocks/CU (73 KB).
// ---------------------------------------------------------------------------
#define KT2 64
#define PP  72

__global__ __launch_bounds__(128, 1) void attn_mfma3(const __bf16* __restrict__ qkv,
                                                     const __bf16* __restrict__ vbT,
                                                     __bf16* __restrict__ y)
{
    __shared__ __bf16 Ks[2][KT2 * 128];
    __shared__ __bf16 VTs[2][128 * KT2];
    __shared__ __bf16 Ps[2][32 * PP];

    const int tid  = threadIdx.x;
    const int wv   = tid >> 6;          // 0..1
    const int lane = tid & 63;
    const int grp  = lane >> 4;
    const int id16 = lane & 15;

    const int bx = blockIdx.x;          // 512 = (B*NH) * 16 pairs
    const int j  = bx & 15;
    const int bh = bx >> 4;
    const int b  = bh >> 4;
    const int h  = bh & 15;
    const int kv = h >> 2;

    const int q0a = j << 6;             // phase-0 q-tile base (64 rows)
    const int q0b = (31 - j) << 6;      // phase-1 q-tile base
    const int NTa = j + 1;
    const int NT  = 33;

    // staging byte offsets (XOR-swizzled), 8 instrs per wave each for K and V
    const int l4 = lane >> 4, l8 = lane >> 3;
    unsigned koff[8], voff[8];
#pragma unroll
    for (int i = 0; i < 8; ++i) {
        int key = wv * 32 + i * 4 + l4;
        int ch  = (lane & 15) ^ ((i * 4 + l4) & 15);
        koff[i] = (unsigned)key * (QKVLD * 2) + ch * 16;
        int d   = wv * 64 + i * 8 + l8;
        int ch2 = (lane & 7) ^ l8;
        voff[i] = (unsigned)d * (T_ * 2) + ch2 * 16;
    }
    const char* kg = (const char*)(qkv + (size_t)b * T_ * QKVLD + KOFF + kv * HD_);
    const char* vg = (const char*)(vbT + ((size_t)(b * NKV_ + kv) * HD_) * T_);

    // Q fragments: qf[qt][c], wave covers rows qv .. qv+31
    bf16x8 qf[2][4];
    {
#pragma unroll
        for (int qt = 0; qt < 2; ++qt) {
            const __bf16* qp = qkv + (size_t)(b * T_ + q0a + wv * 32 + qt * 16 + id16) * QKVLD + h * HD_ + (grp << 3);
#pragma unroll
            for (int c = 0; c < 4; ++c) qf[qt][c] = *(const bf16x8*)(qp + c * 32);
        }
    }

    const f32x4 fz = {0.f, 0.f, 0.f, 0.f};
    f32x4 o[2][8];
#pragma unroll
    for (int qt = 0; qt < 2; ++qt)
#pragma unroll
        for (int c = 0; c < 8; ++c) o[qt][c] = fz;
    float l_acc[2][4];
#pragma unroll
    for (int qt = 0; qt < 2; ++qt)
#pragma unroll
        for (int r = 0; r < 4; ++r) l_acc[qt][r] = 0.f;

    int qv  = q0a + wv * 32;

    // prologue: stage tile 0 into buf 0
    {
        __bf16* kl = &Ks[0][(wv * 32) * 128];
        __bf16* vl = &VTs[0][(wv * 64) * 64];
#pragma unroll
        for (int i = 0; i < 8; ++i) gload_lds16(kg + koff[i], kl + i * 512);
#pragma unroll
        for (int i = 0; i < 8; ++i) gload_lds16(vg + voff[i], vl + i * 512);
    }

    for (int tt = 0; tt < NT; ++tt) {
        const int bufc = tt & 1;
        asm volatile("s_waitcnt vmcnt(0)" ::: "memory");
        __syncthreads();

        // prefetch next tile into the other buffer
        if (tt + 1 < NT) {
            int tn = tt + 1;
            int sn = (tn >= NTa ? tn - NTa : tn) << 6;
            __bf16* kl = &Ks[tn & 1][(wv * 32) * 128];
            __bf16* vl = &VTs[tn & 1][(wv * 64) * 64];
            const char* kp = kg + (size_t)sn * (QKVLD * 2);
            const char* vp = vg + (size_t)sn * 2;
#pragma unroll
            for (int i = 0; i < 8; ++i) gload_lds16(kp + koff[i], kl + i * 512);
#pragma unroll
            for (int i = 0; i < 8; ++i) gload_lds16(vp + voff[i], vl + i * 512);
        }

        // phase switch: write out phase-0 output, reset state, reload Q
        if (tt == NTa) {
#pragma unroll
            for (int qt = 0; qt < 2; ++qt)
#pragma unroll
                for (int r = 0; r < 4; ++r) {
                    float l = l_acc[qt][r];
                    l += __shfl_xor(l, 1, 64);
                    l += __shfl_xor(l, 2, 64);
                    l += __shfl_xor(l, 4, 64);
                    l += __shfl_xor(l, 8, 64);
                    float inv = 1.f / l;
                    int q = qv + qt * 16 + (grp << 2) + r;
                    __bf16* yp = y + (size_t)(b * T_ + q) * C_ + h * HD_ + id16;
#pragma unroll
                    for (int c = 0; c < 8; ++c) yp[c * 16] = (__bf16)(o[qt][c][r] * inv);
                }
#pragma unroll
            for (int qt = 0; qt < 2; ++qt) {
#pragma unroll
                for (int c = 0; c < 8; ++c) o[qt][c] = fz;
#pragma unroll
                for (int r = 0; r < 4; ++r) l_acc[qt][r] = 0.f;
                const __bf16* qp = qkv + (size_t)(b * T_ + q0b + wv * 32 + qt * 16 + id16) * QKVLD + h * HD_ + (grp << 3);
#pragma unroll
                for (int c = 0; c < 4; ++c) qf[qt][c] = *(const bf16x8*)(qp + c * 32);
            }
            qv = q0b + wv * 32;
        }

        const bool diag = (tt == NTa - 1) || (tt == NT - 1);

        // ---- QK^T: S[2 qt][16 rows][64 keys]; each kf feeds 2 MFMAs ----
        f32x4 S[2][4];
#pragma unroll
        for (int qt = 0; qt < 2; ++qt)
#pragma unroll
            for (int t = 0; t < 4; ++t) S[qt][t] = fz;
#pragma unroll
        for (int c = 0; c < 4; ++c) {
#pragma unroll
            for (int t = 0; t < 4; ++t) {
                bf16x8 kf = *(const bf16x8*)&Ks[bufc][(t * 16 + id16) * 128 + ((((c << 2) + grp) ^ id16) << 3)];
                S[0][t] = __builtin_amdgcn_mfma_f32_16x16x32_bf16(qf[0][c], kf, S[0][t], 0, 0, 0);
                S[1][t] = __builtin_amdgcn_mfma_f32_16x16x32_bf16(qf[1][c], kf, S[1][t], 0, 0, 0);
            }
        }
        // causal mask (block-local: keys t*16+id16 vs rows wv*32+qt*16+grp*4+r)
        if (diag) {
#pragma unroll
            for (int qt = 0; qt < 2; ++qt)
#pragma unroll
                for (int t = 0; t < 4; ++t)
#pragma unroll
                    for (int r = 0; r < 4; ++r)
                        if (t * 16 + id16 > wv * 32 + qt * 16 + (grp << 2) + r)
                            S[qt][t][r] = -1e30f;
        }

        // ---- p = exp2(S); per-lane l partials ----
#pragma unroll
        for (int qt = 0; qt < 2; ++qt)
#pragma unroll
            for (int t = 0; t < 4; ++t)
#pragma unroll
                for (int r = 0; r < 4; ++r) S[qt][t][r] = exp2f(S[qt][t][r]);
#pragma unroll
        for (int qt = 0; qt < 2; ++qt)
#pragma unroll
            for (int r = 0; r < 4; ++r)
                l_acc[qt][r] += (S[qt][0][r] + S[qt][1][r]) + (S[qt][2][r] + S[qt][3][r]);

        // ---- P (C layout) -> LDS -> A layout ----
        __bf16* pw = Ps[wv];
#pragma unroll
        for (int qt = 0; qt < 2; ++qt)
#pragma unroll
            for (int t = 0; t < 4; ++t)
#pragma unroll
                for (int r = 0; r < 4; ++r)
                    pw[(qt * 16 + (grp << 2) + r) * PP + t * 16 + id16] = (__bf16)S[qt][t][r];

        asm volatile("s_waitcnt lgkmcnt(0)" ::: "memory");
        bf16x8 pf[2][2];
#pragma unroll
        for (int qt = 0; qt < 2; ++qt)
#pragma unroll
            for (int c = 0; c < 2; ++c)
                pf[qt][c] = *(const bf16x8*)&pw[(qt * 16 + id16) * PP + c * 32 + (grp << 3)];

        // ---- PV: O[qt][16][128] += P[qt][16][64] V[64][128]; vf feeds 2 ----
#pragma unroll
        for (int c = 0; c < 2; ++c) {
#pragma unroll
            for (int dt = 0; dt < 8; ++dt) {
                bf16x8 vf = *(const bf16x8*)&VTs[bufc][(dt * 16 + id16) * 64 + ((((c << 2) + grp) ^ (id16 & 7)) << 3)];
                o[0][dt] = __builtin_amdgcn_mfma_f32_16x16x32_bf16(pf[0][c], vf, o[0][dt], 0, 0, 0);
                o[1][dt] = __builtin_amdgcn_mfma_f32_16x16x32_bf16(pf[1][c], vf, o[1][dt], 0, 0, 0);
            }
        }
    }

    // final epilogue (phase 1)
#pragma unroll
    for (int qt = 0; qt < 2; ++qt)
#pragma unroll
        for (int r = 0; r < 4; ++r) {
            float l = l_acc[qt][r];
            l += __shfl_xor(l, 1, 64);
            l += __shfl_xor(l, 2, 64);
            l += __shfl_xor(l, 4, 64);
            l += __shfl_xor(l, 8, 64);
            float inv = 1.f / l;
            int q = qv + qt * 16 + (grp << 2) + r;
            __bf16* yp = y + (size_t)(b * T_ + q) * C_ + h * HD_ + id16;
#pragma unroll
            for (int c = 0; c < 8; ++c) yp[c * 16] = (__bf16)(o[qt][c][r] * inv);
        }
}

// ---------------------------------------------------------------------------
extern "C" void kernel_launch(void* const* d_in, const int* in_sizes, int n_in,
                              void* d_out, int out_size, void* d_ws, size_t ws_size,
                              hipStream_t stream)
{
    const float* x    = (const float*)d_in[0];
    const float* cosb = (const float*)d_in[1];
    const float* sinb = (const float*)d_in[2];
    const float* Wq   = (const float*)d_in[3];
    const float* Wk   = (const float*)d_in[4];
    const float* Wv   = (const float*)d_in[5];
    const float* Wp   = (const float*)d_in[6];
    float* out = (float*)d_out;

    const int M = B_ * T_;   // 4096

    // workspace: xb | qkv | wqkvT | wpT | vt | y   (all bf16)  ~= 84 MB
    char* w = (char*)d_ws;
    __bf16* xb    = (__bf16*)w;  w += (size_t)M * C_ * 2;
    __bf16* qkv   = (__bf16*)w;  w += (size_t)M * QKVLD * 2;
    __bf16* wqkvT = (__bf16*)w;  w += (size_t)QKVLD * C_ * 2;
    __bf16* wpT   = (__bf16*)w;  w += (size_t)C_ * C_ * 2;
    __bf16* vt    = (__bf16*)w;  w += (size_t)M * NKV_ * HD_ * 2;
    __bf16* y     = (__bf16*)w;

    // casts / transposes
    cast_bf16<<<(M * C_) / 2048, 256, 0, stream>>>(x, xb);
    wtrans_qkv<<<dim3(96, C_ / 32), 256, 0, stream>>>(Wq, Wk, Wv, wqkvT);
    wtrans<<<dim3(C_ / 32, C_ / 32), 256, 0, stream>>>(Wp, wpT, C_);

    // fused QKV projection (bf16 MFMA, dbuf)
    gemm_bt<__bf16><<<dim3(QKVLD / 128, M / 128), 256, 0, stream>>>(xb, wqkvT, qkv, M, QKVLD, C_, QKVLD);

    // RoPE + RMSNorm in-place (q gets 1/128 * log2e; k plain)
    rope_rms_b<<<(M * NH_) / 4, 256, 0, stream>>>(qkv, cosb, sinb, NH_, QSCALE);
    rope_rms_b<<<(M * NKV_) / 4, 256, 0, stream>>>(qkv + KOFF, cosb, sinb, NKV_, 1.0f);

    // V transpose to [B,KV,128,T]
    vtrans<<<B_ * NKV_ * (T_ / 32), 256, 0, stream>>>(qkv, vt);

    // flash attention v4 (2 waves x 32q, 2x fragment reuse), bf16 y out
    attn_mfma3<<<B_ * NH_ * 16, 128, 0, stream>>>(qkv, vt, y);

    // output projection (bf16 MFMA, fp32 out, dbuf)
    gemm_bt<float><<<dim3(C_ / 128, M / 128), 256, 0, stream>>>(y, wpT, out, M, C_, C_, C_);
}